// Round 6
// baseline (212.512 us; speedup 1.0000x reference)
//
#include <hip/hip_runtime.h>
#include <math.h>

#define EDIM 256
#define LDIM 1024
#define HDIM 8
#define DDIM 32

typedef __attribute__((ext_vector_type(8))) short short8;
typedef __attribute__((ext_vector_type(4))) float f32x4;

__device__ inline unsigned short bf16h(float x) {
    unsigned u = __float_as_uint(x);
    return (unsigned short)((u + 0x7fff + ((u >> 16) & 1)) >> 16);   // RNE
}
__device__ inline float bf16tof(unsigned short h) {
    return __uint_as_float(((unsigned)h) << 16);
}
// split 8 fp32 (two float4) into hi/lo bf16 short8
__device__ inline void split8(const float4& a, const float4& b, short8& hi, short8& lo) {
    float v[8] = {a.x,a.y,a.z,a.w, b.x,b.y,b.z,b.w};
    #pragma unroll
    for (int j = 0; j < 8; ++j) {
        unsigned short hh = bf16h(v[j]);
        hi[j] = (short)hh;
        lo[j] = (short)bf16h(v[j] - bf16tof(hh));
    }
}

// ---------------------------------------------------------------------------
// convertw_kernel: split the 4 weight matrices (E x E) into hi/lo bf16.
// grid (32, 4): 8 elems/thread.
// ---------------------------------------------------------------------------
__global__ __launch_bounds__(256) void convertw_kernel(
    const float* __restrict__ Wq, const float* __restrict__ Wk,
    const float* __restrict__ Wv, const float* __restrict__ Wo,
    short* __restrict__ Wqh, short* __restrict__ Wql,
    short* __restrict__ Wkh, short* __restrict__ Wkl,
    short* __restrict__ Wvh, short* __restrict__ Wvl,
    short* __restrict__ Woh, short* __restrict__ Wol)
{
    const int z = blockIdx.y;
    const float* src; short* dh; short* dl;
    switch (z) {
        case 0: src = Wq; dh = Wqh; dl = Wql; break;
        case 1: src = Wk; dh = Wkh; dl = Wkl; break;
        case 2: src = Wv; dh = Wvh; dl = Wvl; break;
        default: src = Wo; dh = Woh; dl = Wol; break;
    }
    const int idx = (blockIdx.x * 256 + threadIdx.x) * 8;
    float4 a = *(const float4*)(src + idx);
    float4 b = *(const float4*)(src + idx + 4);
    short8 hi, lo;
    split8(a, b, hi, lo);
    *(short8*)&dh[idx] = hi;
    *(short8*)&dl[idx] = lo;
}

// ---------------------------------------------------------------------------
// proj_kernel (MFMA): dst(H,L,D) = X(L,E) @ W(E,E)^T per blockIdx.z.
// split-bf16 3-term MFMA; A-fragments converted in-register from fp32 X
// (direct 16B global frag loads, no LDS, no barriers). 32x64 tile, 128 thr
// (2 waves x 16-row strips x 4 col-tiles), grid (32,4,3) = 384 blocks.
// z==0 fuses coeff[h][r] = sum_d q[r,h,d]*Wr[h*32+d].
// ---------------------------------------------------------------------------
__global__ __launch_bounds__(128) void proj_kernel(
    const float* __restrict__ Q, const float* __restrict__ K, const float* __restrict__ V,
    const short* __restrict__ Wqh, const short* __restrict__ Wql,
    const short* __restrict__ Wkh, const short* __restrict__ Wkl,
    const short* __restrict__ Wvh, const short* __restrict__ Wvl,
    const float* __restrict__ Wr,
    float* __restrict__ qT, float* __restrict__ kT, float* __restrict__ vT,
    float* __restrict__ coeff)
{
    const int z = blockIdx.z;
    const float* __restrict__ X  = (z == 0) ? Q : (z == 1) ? K : V;
    const short* __restrict__ Wh = (z == 0) ? Wqh : (z == 1) ? Wkh : Wvh;
    const short* __restrict__ Wl = (z == 0) ? Wql : (z == 1) ? Wkl : Wvl;
    float* __restrict__ dst      = (z == 0) ? qT : (z == 1) ? kT : vT;

    const int n0 = blockIdx.x * 32;
    const int o0 = blockIdx.y * 64;
    const int wave = threadIdx.x >> 6;
    const int lane = threadIdx.x & 63;
    const int n16  = lane & 15;
    const int quad = lane >> 4;

    const int mrow = n0 + wave*16 + n16;

    f32x4 acc[4];
    #pragma unroll
    for (int t4 = 0; t4 < 4; ++t4) acc[t4] = (f32x4){0.f,0.f,0.f,0.f};

    #pragma unroll 2
    for (int kb = 0; kb < EDIM; kb += 32) {
        const float* xp = X + mrow*EDIM + kb + quad*8;
        float4 a0 = *(const float4*)xp;
        float4 a1 = *(const float4*)(xp + 4);
        short8 ah, al;
        split8(a0, a1, ah, al);
        #pragma unroll
        for (int t4 = 0; t4 < 4; ++t4) {
            const int orow = o0 + 16*t4 + n16;
            short8 bh = *(const short8*)&Wh[orow*EDIM + kb + quad*8];
            short8 bl = *(const short8*)&Wl[orow*EDIM + kb + quad*8];
            acc[t4] = __builtin_amdgcn_mfma_f32_16x16x32_bf16(al, bh, acc[t4], 0, 0, 0);
            acc[t4] = __builtin_amdgcn_mfma_f32_16x16x32_bf16(ah, bl, acc[t4], 0, 0, 0);
            acc[t4] = __builtin_amdgcn_mfma_f32_16x16x32_bf16(ah, bh, acc[t4], 0, 0, 0);
        }
    }

    // C/D layout: row = quad*4+i, col = n16 (per 16-col tile)
    #pragma unroll
    for (int t4 = 0; t4 < 4; ++t4) {
        const int o = o0 + 16*t4 + n16;
        const int h = o >> 5, d = o & 31;
        #pragma unroll
        for (int i = 0; i < 4; ++i) {
            const int r = n0 + wave*16 + quad*4 + i;
            dst[h*(LDIM*DDIM) + r*DDIM + d] = acc[t4][i];
        }
    }

    if (z == 0) {
        float wr[4];
        #pragma unroll
        for (int t4 = 0; t4 < 4; ++t4) wr[t4] = Wr[o0 + 16*t4 + n16];
        const int h0 = o0 >> 5;
        #pragma unroll
        for (int i = 0; i < 4; ++i) {
            float c0 = acc[0][i]*wr[0] + acc[1][i]*wr[1];
            float c1 = acc[2][i]*wr[2] + acc[3][i]*wr[3];
            #pragma unroll
            for (int off = 1; off < 16; off <<= 1) {
                c0 += __shfl_xor(c0, off, 64);
                c1 += __shfl_xor(c1, off, 64);
            }
            if (n16 == 0) {
                const int r = n0 + wave*16 + quad*4 + i;
                coeff[h0*LDIM + r]     = c0;
                coeff[(h0+1)*LDIM + r] = c1;
            }
        }
    }
}

// ---------------------------------------------------------------------------
// attn_kernel: flash attention, QK^T on MFMA (split-bf16), softmax in C/D
// layout, PV on VALU via transposed P in LDS. Grid (16, H, P). After writing
// partials, the LAST block per (h, q-block) (device-scope atomic counter)
// combines the P partials and emits split-bf16 A directly (no extra launch).
// ---------------------------------------------------------------------------
__global__ __launch_bounds__(256, 4) void attn_kernel(
    const float* __restrict__ qT, const float* __restrict__ kT, const float* __restrict__ vT,
    const float* __restrict__ coeff, const float* __restrict__ pos,
    float* __restrict__ Op, float* __restrict__ Mp, float* __restrict__ Lp,
    int* __restrict__ counters, short* __restrict__ Ah, short* __restrict__ Al, int nkt)
{
    const int h   = blockIdx.y;
    const int q0  = blockIdx.x * 64;
    const int p   = blockIdx.z;
    const int P   = gridDim.z;
    const int kt0 = p * nkt * 64;
    const int tid  = threadIdx.x;
    const int wave = tid >> 6;
    const int lane = tid & 63;
    const int n    = lane & 15;
    const int quad = lane >> 4;
    const int qs0  = wave * 16;

    __shared__ __align__(16) short khi[4*64*8];
    __shared__ __align__(16) short klo[4*64*8];
    __shared__ float vs[64][36];
    __shared__ float ps_t[64][68];
    __shared__ float alph[64];
    __shared__ float pk[64];

    short8 qhi, qlo;
    {
        const float* qp = qT + (h*LDIM + q0 + qs0 + n) * DDIM + quad*8;
        float4 qa = *(const float4*)qp;
        float4 qb = *(const float4*)(qp + 4);
        split8(qa, qb, qhi, qlo);
    }

    float pq[4], cq[4];
    #pragma unroll
    for (int i = 0; i < 4; ++i) {
        const int r = q0 + qs0 + 4*quad + i;
        pq[i] = pos[r];
        cq[i] = coeff[h*LDIM + r] * 0.0625f;
    }

    float m[4], l[4];
    #pragma unroll
    for (int i = 0; i < 4; ++i) { m[i] = -INFINITY; l[i] = 0.f; }

    const int pr0 = (tid >> 4) * 4;
    const int dg2 = (tid & 15) * 2;
    float o[4][2];
    #pragma unroll
    for (int i = 0; i < 4; ++i) { o[i][0] = 0.f; o[i][1] = 0.f; }

    const int cS = tid >> 2;
    const int dq = tid & 3;
    const int lane2 = (cS & 15) | (dq << 4);
    const int gS = cS >> 4;

    float4 k0c, k1c, v0c, v1c; float pkc = 0.f;
    {
        const float* kp = kT + (h*LDIM + kt0 + cS) * DDIM + dq*8;
        k0c = *(const float4*)kp; k1c = *(const float4*)(kp + 4);
        const float* vp = vT + (h*LDIM + kt0 + cS) * DDIM + dq*8;
        v0c = *(const float4*)vp; v1c = *(const float4*)(vp + 4);
        if (tid < 64) pkc = pos[kt0 + tid];
    }

    for (int t = 0; t < nkt; ++t) {
        __syncthreads();   // (A) prev consumers done

        {
            short8 hi8, lo8;
            split8(k0c, k1c, hi8, lo8);
            *((short8*)&khi[(gS*64 + lane2)*8]) = hi8;
            *((short8*)&klo[(gS*64 + lane2)*8]) = lo8;
            *(float4*)&vs[cS][dq*8]     = v0c;
            *(float4*)&vs[cS][dq*8 + 4] = v1c;
            if (tid < 64) pk[tid] = pkc;
        }

        float4 k0n, k1n, v0n, v1n; float pkn = 0.f;
        if (t + 1 < nkt) {
            const int kt = kt0 + (t+1) * 64;
            const float* kp = kT + (h*LDIM + kt + cS) * DDIM + dq*8;
            k0n = *(const float4*)kp; k1n = *(const float4*)(kp + 4);
            const float* vp = vT + (h*LDIM + kt + cS) * DDIM + dq*8;
            v0n = *(const float4*)vp; v1n = *(const float4*)(vp + 4);
            if (tid < 64) pkn = pos[kt + tid];
        }
        __syncthreads();   // (B) staging visible

        f32x4 Sf[4];
        #pragma unroll
        for (int t4 = 0; t4 < 4; ++t4) {
            short8 bhi = *((const short8*)&khi[(t4*64 + lane)*8]);
            short8 blo = *((const short8*)&klo[(t4*64 + lane)*8]);
            f32x4 acc = {0.f, 0.f, 0.f, 0.f};
            acc = __builtin_amdgcn_mfma_f32_16x16x32_bf16(qlo, bhi, acc, 0, 0, 0);
            acc = __builtin_amdgcn_mfma_f32_16x16x32_bf16(qhi, blo, acc, 0, 0, 0);
            acc = __builtin_amdgcn_mfma_f32_16x16x32_bf16(qhi, bhi, acc, 0, 0, 0);
            Sf[t4] = acc;
        }

        float ev[4][4];
        float rmax[4] = {-INFINITY, -INFINITY, -INFINITY, -INFINITY};
        #pragma unroll
        for (int t4 = 0; t4 < 4; ++t4) {
            const float pkt = pk[16*t4 + n];
            #pragma unroll
            for (int i = 0; i < 4; ++i) {
                float s = fmaf(Sf[t4][i], 0.0625f, cq[i] * __logf(fabsf(pq[i] - pkt) + 1.f));
                ev[t4][i] = s;
                rmax[i] = fmaxf(rmax[i], s);
            }
        }
        #pragma unroll
        for (int off = 1; off < 16; off <<= 1)
            #pragma unroll
            for (int i = 0; i < 4; ++i)
                rmax[i] = fmaxf(rmax[i], __shfl_xor(rmax[i], off, 64));

        float al[4], rsum[4];
        #pragma unroll
        for (int i = 0; i < 4; ++i) {
            const float mn = fmaxf(m[i], rmax[i]);
            al[i] = __expf(m[i] - mn);
            m[i] = mn;
            rsum[i] = 0.f;
        }
        #pragma unroll
        for (int t4 = 0; t4 < 4; ++t4)
            #pragma unroll
            for (int i = 0; i < 4; ++i) {
                float e = __expf(ev[t4][i] - m[i]);
                ev[t4][i] = e;
                rsum[i] += e;
            }
        #pragma unroll
        for (int off = 1; off < 16; off <<= 1)
            #pragma unroll
            for (int i = 0; i < 4; ++i)
                rsum[i] += __shfl_xor(rsum[i], off, 64);
        #pragma unroll
        for (int i = 0; i < 4; ++i) l[i] = l[i]*al[i] + rsum[i];

        if (n == 0) {
            #pragma unroll
            for (int i = 0; i < 4; ++i) alph[qs0 + 4*quad + i] = al[i];
        }
        #pragma unroll
        for (int t4 = 0; t4 < 4; ++t4) {
            float4 w; w.x = ev[t4][0]; w.y = ev[t4][1]; w.z = ev[t4][2]; w.w = ev[t4][3];
            *(float4*)&ps_t[16*t4 + n][qs0 + 4*quad] = w;
        }
        __syncthreads();   // (C) ps_t/alph visible

        {
            float4 a4 = *(const float4*)&alph[pr0];
            o[0][0]*=a4.x; o[0][1]*=a4.x; o[1][0]*=a4.y; o[1][1]*=a4.y;
            o[2][0]*=a4.z; o[2][1]*=a4.z; o[3][0]*=a4.w; o[3][1]*=a4.w;
        }
        #pragma unroll 4
        for (int c = 0; c < 64; ++c) {
            float4 p4 = *(const float4*)&ps_t[c][pr0];
            float2 v2 = *(const float2*)&vs[c][dg2];
            o[0][0] += p4.x*v2.x; o[0][1] += p4.x*v2.y;
            o[1][0] += p4.y*v2.x; o[1][1] += p4.y*v2.y;
            o[2][0] += p4.z*v2.x; o[2][1] += p4.z*v2.y;
            o[3][0] += p4.w*v2.x; o[3][1] += p4.w*v2.y;
        }

        k0c = k0n; k1c = k1n; v0c = v0n; v1c = v1n; pkc = pkn;
    }

    // ---- write partials ----
    const int ph = p * HDIM + h;
    #pragma unroll
    for (int i = 0; i < 4; ++i) {
        float2 w; w.x = o[i][0]; w.y = o[i][1];
        *(float2*)(Op + ((size_t)ph*LDIM + q0 + pr0 + i)*DDIM + dg2) = w;
    }
    if (n == 0) {
        #pragma unroll
        for (int i = 0; i < 4; ++i) {
            const int r = q0 + qs0 + 4*quad + i;
            Mp[ph*LDIM + r] = m[i];
            Lp[ph*LDIM + r] = l[i];
        }
    }

    // ---- last-block-per-(h,q-block) combine -> split-bf16 A ----
    __threadfence();                       // release our partials (agent scope)
    __shared__ int ticket;
    __syncthreads();                       // all writes fenced before the atomic
    if (tid == 0) ticket = atomicAdd(&counters[h*16 + blockIdx.x], 1);
    __syncthreads();
    if (ticket == P - 1) {
        __threadfence();                   // acquire others' partials
        const int r  = q0 + (tid >> 2);    // 64 rows x 4 d-chunks = 256 threads
        const int d0 = (tid & 3) * 8;

        float mv[8], lv[8];
        float mx = -INFINITY;
        #pragma unroll
        for (int pp = 0; pp < 8; ++pp) if (pp < P) {
            mv[pp] = Mp[(pp*HDIM + h)*LDIM + r];
            lv[pp] = Lp[(pp*HDIM + h)*LDIM + r];
            mx = fmaxf(mx, mv[pp]);
        }
        float s = 0.f;
        #pragma unroll
        for (int pp = 0; pp < 8; ++pp) if (pp < P) {
            float a = __expf(mv[pp] - mx);
            mv[pp] = a;
            s += a * lv[pp];
        }
        const float inv = 1.f / s;

        float x[8] = {0.f,0.f,0.f,0.f, 0.f,0.f,0.f,0.f};
        #pragma unroll
        for (int pp = 0; pp < 8; ++pp) if (pp < P) {
            const float sp = mv[pp] * inv;
            const float* ob = Op + ((size_t)(pp*HDIM + h)*LDIM + r)*DDIM + d0;
            float4 x0 = *(const float4*)ob;
            float4 x1 = *(const float4*)(ob + 4);
            x[0] += sp*x0.x; x[1] += sp*x0.y; x[2] += sp*x0.z; x[3] += sp*x0.w;
            x[4] += sp*x1.x; x[5] += sp*x1.y; x[6] += sp*x1.z; x[7] += sp*x1.w;
        }
        short8 hi, lo;
        #pragma unroll
        for (int j = 0; j < 8; ++j) {
            unsigned short hh = bf16h(x[j]);
            hi[j] = (short)hh;
            lo[j] = (short)bf16h(x[j] - bf16tof(hh));
        }
        *(short8*)&Ah[r*EDIM + h*DDIM + d0] = hi;
        *(short8*)&Al[r*EDIM + h*DDIM + d0] = lo;
    }
}

// ---------------------------------------------------------------------------
// outproj_kernel (MFMA): out(L,E) = A(L,E) @ Wo(E,E)^T + bo, split-bf16
// 3-term MFMA, direct global fragment loads. 32x32 tile, 128 thr (2 waves x
// 2 col-tiles), grid (32,8) = 256 blocks.
// ---------------------------------------------------------------------------
__global__ __launch_bounds__(128) void outproj_kernel(
    const short* __restrict__ Ah, const short* __restrict__ Al,
    const short* __restrict__ Woh, const short* __restrict__ Wol,
    const float* __restrict__ bo, float* __restrict__ out)
{
    const int n0 = blockIdx.x * 32;
    const int o0 = blockIdx.y * 32;
    const int wave = threadIdx.x >> 6;
    const int lane = threadIdx.x & 63;
    const int n16  = lane & 15;
    const int quad = lane >> 4;

    const int mrow = n0 + wave*16 + n16;

    f32x4 acc[2];
    acc[0] = (f32x4){0.f,0.f,0.f,0.f};
    acc[1] = (f32x4){0.f,0.f,0.f,0.f};

    #pragma unroll 2
    for (int kb = 0; kb < EDIM; kb += 32) {
        short8 ah = *(const short8*)&Ah[mrow*EDIM + kb + quad*8];
        short8 al = *(const short8*)&Al[mrow*EDIM + kb + quad*8];
        #pragma unroll
        for (int t2 = 0; t2 < 2; ++t2) {
            const int orow = o0 + 16*t2 + n16;
            short8 bh = *(const short8*)&Woh[orow*EDIM + kb + quad*8];
            short8 bl = *(const short8*)&Wol[orow*EDIM + kb + quad*8];
            acc[t2] = __builtin_amdgcn_mfma_f32_16x16x32_bf16(al, bh, acc[t2], 0, 0, 0);
            acc[t2] = __builtin_amdgcn_mfma_f32_16x16x32_bf16(ah, bl, acc[t2], 0, 0, 0);
            acc[t2] = __builtin_amdgcn_mfma_f32_16x16x32_bf16(ah, bh, acc[t2], 0, 0, 0);
        }
    }

    #pragma unroll
    for (int t2 = 0; t2 < 2; ++t2) {
        const int o = o0 + 16*t2 + n16;
        const float b = bo[o];
        #pragma unroll
        for (int i = 0; i < 4; ++i) {
            const int r = n0 + wave*16 + quad*4 + i;
            out[r*EDIM + o] = acc[t2][i] + b;
        }
    }
}

// ---------------------------------------------------------------------------
extern "C" void kernel_launch(void* const* d_in, const int* in_sizes, int n_in,
                              void* d_out, int out_size, void* d_ws, size_t ws_size,
                              hipStream_t stream) {
    const float* V   = (const float*)d_in[0];
    const float* K   = (const float*)d_in[1];
    const float* Q   = (const float*)d_in[2];
    const float* pos = (const float*)d_in[3];
    const float* Wq  = (const float*)d_in[4];
    const float* Wk  = (const float*)d_in[5];
    const float* Wv  = (const float*)d_in[6];
    const float* Wr  = (const float*)d_in[7];
    const float* Wo  = (const float*)d_in[8];
    const float* bo  = (const float*)d_in[9];
    float* out = (float*)d_out;
    float* ws  = (float*)d_ws;

    // ---- workspace layout (float units) ----
    short* Wqh = (short*)(ws);          short* Wql = (short*)(ws + 32768);
    short* Wkh = (short*)(ws + 65536);  short* Wkl = (short*)(ws + 98304);
    short* Wvh = (short*)(ws + 131072); short* Wvl = (short*)(ws + 163840);
    short* Woh = (short*)(ws + 196608); short* Wol = (short*)(ws + 229376);
    float* qT    = ws + 262144;
    float* kT    = ws + 524288;
    float* vT    = ws + 786432;
    float* coeff = ws + 1048576;
    short* Ah    = (short*)(ws + 1056768);   // 262144 shorts
    short* Al    = (short*)(ws + 1187840);
    int*   counters = (int*)(ws + 1318912);  // 128 ints
    float* Op    = ws + 1319040;

    auto need = [](int P) -> size_t {
        return (size_t)(1319040 + P*278528) * 4;
    };
    int P = 2;
    if (ws_size >= need(8)) P = 8;
    else if (ws_size >= need(4)) P = 4;

    float* Mp = Op + (size_t)P * 262144;
    float* Lp = Mp + (size_t)P * 8192;

    hipMemsetAsync(counters, 0, 128 * sizeof(int), stream);
    convertw_kernel<<<dim3(32, 4),    256, 0, stream>>>(Wq, Wk, Wv, Wo,
        Wqh, Wql, Wkh, Wkl, Wvh, Wvl, Woh, Wol);
    proj_kernel    <<<dim3(32, 4, 3), 128, 0, stream>>>(Q, K, V,
        Wqh, Wql, Wkh, Wkl, Wvh, Wvl, Wr, qT, kT, vT, coeff);
    attn_kernel    <<<dim3(16, 8, P), 256, 0, stream>>>(qT, kT, vT, coeff, pos,
        Op, Mp, Lp, counters, Ah, Al, 16 / P);
    outproj_kernel <<<dim3(32, 8),    128, 0, stream>>>(Ah, Al, Woh, Wol, bo, out);
}

// Round 7
// 124.415 us; speedup vs baseline: 1.7081x; 1.7081x over previous
//
#include <hip/hip_runtime.h>
#include <math.h>

#define EDIM 256
#define LDIM 1024
#define HDIM 8
#define DDIM 32

typedef __attribute__((ext_vector_type(8))) short short8;
typedef __attribute__((ext_vector_type(4))) short short4v;
typedef __attribute__((ext_vector_type(4))) float f32x4;

__device__ inline unsigned short bf16h(float x) {
    unsigned u = __float_as_uint(x);
    return (unsigned short)((u + 0x7fff + ((u >> 16) & 1)) >> 16);   // RNE
}
__device__ inline float bf16tof(unsigned short h) {
    return __uint_as_float(((unsigned)h) << 16);
}
// split 8 fp32 (two float4) into hi/lo bf16 short8
__device__ inline void split8(const float4& a, const float4& b, short8& hi, short8& lo) {
    float v[8] = {a.x,a.y,a.z,a.w, b.x,b.y,b.z,b.w};
    #pragma unroll
    for (int j = 0; j < 8; ++j) {
        unsigned short hh = bf16h(v[j]);
        hi[j] = (short)hh;
        lo[j] = (short)bf16h(v[j] - bf16tof(hh));
    }
}

// ---------------------------------------------------------------------------
// convertw_kernel: split the 4 weight matrices (E x E) into hi/lo bf16.
// grid (32, 4): 8 elems/thread.
// ---------------------------------------------------------------------------
__global__ __launch_bounds__(256) void convertw_kernel(
    const float* __restrict__ Wq, const float* __restrict__ Wk,
    const float* __restrict__ Wv, const float* __restrict__ Wo,
    short* __restrict__ Wqh, short* __restrict__ Wql,
    short* __restrict__ Wkh, short* __restrict__ Wkl,
    short* __restrict__ Wvh, short* __restrict__ Wvl,
    short* __restrict__ Woh, short* __restrict__ Wol)
{
    const int z = blockIdx.y;
    const float* src; short* dh; short* dl;
    switch (z) {
        case 0: src = Wq; dh = Wqh; dl = Wql; break;
        case 1: src = Wk; dh = Wkh; dl = Wkl; break;
        case 2: src = Wv; dh = Wvh; dl = Wvl; break;
        default: src = Wo; dh = Woh; dl = Wol; break;
    }
    const int idx = (blockIdx.x * 256 + threadIdx.x) * 8;
    float4 a = *(const float4*)(src + idx);
    float4 b = *(const float4*)(src + idx + 4);
    short8 hi, lo;
    split8(a, b, hi, lo);
    *(short8*)&dh[idx] = hi;
    *(short8*)&dl[idx] = lo;
}

// ---------------------------------------------------------------------------
// proj_kernel (MFMA): dst(H,L,D) = X(L,E) @ W(E,E)^T per blockIdx.z.
// split-bf16 3-term MFMA; A-fragments converted in-register from fp32 X
// (direct 16B global frag loads, no LDS, no barriers). 32x64 tile, 128 thr
// (2 waves x 16-row strips x 4 col-tiles), grid (32,4,3) = 384 blocks.
// z==0 fuses coeff[h][r] = sum_d q[r,h,d]*Wr[h*32+d].
// ---------------------------------------------------------------------------
__global__ __launch_bounds__(128) void proj_kernel(
    const float* __restrict__ Q, const float* __restrict__ K, const float* __restrict__ V,
    const short* __restrict__ Wqh, const short* __restrict__ Wql,
    const short* __restrict__ Wkh, const short* __restrict__ Wkl,
    const short* __restrict__ Wvh, const short* __restrict__ Wvl,
    const float* __restrict__ Wr,
    float* __restrict__ qT, float* __restrict__ kT, float* __restrict__ vT,
    float* __restrict__ coeff)
{
    const int z = blockIdx.z;
    const float* __restrict__ X  = (z == 0) ? Q : (z == 1) ? K : V;
    const short* __restrict__ Wh = (z == 0) ? Wqh : (z == 1) ? Wkh : Wvh;
    const short* __restrict__ Wl = (z == 0) ? Wql : (z == 1) ? Wkl : Wvl;
    float* __restrict__ dst      = (z == 0) ? qT : (z == 1) ? kT : vT;

    const int n0 = blockIdx.x * 32;
    const int o0 = blockIdx.y * 64;
    const int wave = threadIdx.x >> 6;
    const int lane = threadIdx.x & 63;
    const int n16  = lane & 15;
    const int quad = lane >> 4;

    const int mrow = n0 + wave*16 + n16;

    f32x4 acc[4];
    #pragma unroll
    for (int t4 = 0; t4 < 4; ++t4) acc[t4] = (f32x4){0.f,0.f,0.f,0.f};

    #pragma unroll 2
    for (int kb = 0; kb < EDIM; kb += 32) {
        const float* xp = X + mrow*EDIM + kb + quad*8;
        float4 a0 = *(const float4*)xp;
        float4 a1 = *(const float4*)(xp + 4);
        short8 ah, al;
        split8(a0, a1, ah, al);
        #pragma unroll
        for (int t4 = 0; t4 < 4; ++t4) {
            const int orow = o0 + 16*t4 + n16;
            short8 bh = *(const short8*)&Wh[orow*EDIM + kb + quad*8];
            short8 bl = *(const short8*)&Wl[orow*EDIM + kb + quad*8];
            acc[t4] = __builtin_amdgcn_mfma_f32_16x16x32_bf16(al, bh, acc[t4], 0, 0, 0);
            acc[t4] = __builtin_amdgcn_mfma_f32_16x16x32_bf16(ah, bl, acc[t4], 0, 0, 0);
            acc[t4] = __builtin_amdgcn_mfma_f32_16x16x32_bf16(ah, bh, acc[t4], 0, 0, 0);
        }
    }

    // C/D layout: row = quad*4+i, col = n16 (per 16-col tile)
    #pragma unroll
    for (int t4 = 0; t4 < 4; ++t4) {
        const int o = o0 + 16*t4 + n16;
        const int h = o >> 5, d = o & 31;
        #pragma unroll
        for (int i = 0; i < 4; ++i) {
            const int r = n0 + wave*16 + quad*4 + i;
            dst[h*(LDIM*DDIM) + r*DDIM + d] = acc[t4][i];
        }
    }

    if (z == 0) {
        float wr[4];
        #pragma unroll
        for (int t4 = 0; t4 < 4; ++t4) wr[t4] = Wr[o0 + 16*t4 + n16];
        const int h0 = o0 >> 5;
        #pragma unroll
        for (int i = 0; i < 4; ++i) {
            float c0 = acc[0][i]*wr[0] + acc[1][i]*wr[1];
            float c1 = acc[2][i]*wr[2] + acc[3][i]*wr[3];
            #pragma unroll
            for (int off = 1; off < 16; off <<= 1) {
                c0 += __shfl_xor(c0, off, 64);
                c1 += __shfl_xor(c1, off, 64);
            }
            if (n16 == 0) {
                const int r = n0 + wave*16 + quad*4 + i;
                coeff[h0*LDIM + r]     = c0;
                coeff[(h0+1)*LDIM + r] = c1;
            }
        }
    }
}

// ---------------------------------------------------------------------------
// attn_kernel: flash attention, QK^T on MFMA (split-bf16), softmax in C/D
// layout, PV on VALU via transposed P in LDS. Grid (16, H, P). Writes
// unnormalized O partials + (m, l). NO device-scope fences (R6 lesson:
// __threadfence on gfx950 = L2 writeback across XCDs, 15x slowdown).
// ---------------------------------------------------------------------------
__global__ __launch_bounds__(256, 4) void attn_kernel(
    const float* __restrict__ qT, const float* __restrict__ kT, const float* __restrict__ vT,
    const float* __restrict__ coeff, const float* __restrict__ pos,
    float* __restrict__ Op, float* __restrict__ Mp, float* __restrict__ Lp, int nkt)
{
    const int h   = blockIdx.y;
    const int q0  = blockIdx.x * 64;
    const int p   = blockIdx.z;
    const int kt0 = p * nkt * 64;
    const int tid  = threadIdx.x;
    const int wave = tid >> 6;
    const int lane = tid & 63;
    const int n    = lane & 15;
    const int quad = lane >> 4;
    const int qs0  = wave * 16;

    __shared__ __align__(16) short khi[4*64*8];
    __shared__ __align__(16) short klo[4*64*8];
    __shared__ float vs[64][36];
    __shared__ float ps_t[64][68];
    __shared__ float alph[64];
    __shared__ float pk[64];

    short8 qhi, qlo;
    {
        const float* qp = qT + (h*LDIM + q0 + qs0 + n) * DDIM + quad*8;
        float4 qa = *(const float4*)qp;
        float4 qb = *(const float4*)(qp + 4);
        split8(qa, qb, qhi, qlo);
    }

    float pq[4], cq[4];
    #pragma unroll
    for (int i = 0; i < 4; ++i) {
        const int r = q0 + qs0 + 4*quad + i;
        pq[i] = pos[r];
        cq[i] = coeff[h*LDIM + r] * 0.0625f;
    }

    float m[4], l[4];
    #pragma unroll
    for (int i = 0; i < 4; ++i) { m[i] = -INFINITY; l[i] = 0.f; }

    const int pr0 = (tid >> 4) * 4;
    const int dg2 = (tid & 15) * 2;
    float o[4][2];
    #pragma unroll
    for (int i = 0; i < 4; ++i) { o[i][0] = 0.f; o[i][1] = 0.f; }

    const int cS = tid >> 2;
    const int dq = tid & 3;
    const int lane2 = (cS & 15) | (dq << 4);
    const int gS = cS >> 4;

    float4 k0c, k1c, v0c, v1c; float pkc = 0.f;
    {
        const float* kp = kT + (h*LDIM + kt0 + cS) * DDIM + dq*8;
        k0c = *(const float4*)kp; k1c = *(const float4*)(kp + 4);
        const float* vp = vT + (h*LDIM + kt0 + cS) * DDIM + dq*8;
        v0c = *(const float4*)vp; v1c = *(const float4*)(vp + 4);
        if (tid < 64) pkc = pos[kt0 + tid];
    }

    for (int t = 0; t < nkt; ++t) {
        __syncthreads();   // (A) prev consumers done

        {
            short8 hi8, lo8;
            split8(k0c, k1c, hi8, lo8);
            *((short8*)&khi[(gS*64 + lane2)*8]) = hi8;
            *((short8*)&klo[(gS*64 + lane2)*8]) = lo8;
            *(float4*)&vs[cS][dq*8]     = v0c;
            *(float4*)&vs[cS][dq*8 + 4] = v1c;
            if (tid < 64) pk[tid] = pkc;
        }

        float4 k0n, k1n, v0n, v1n; float pkn = 0.f;
        if (t + 1 < nkt) {
            const int kt = kt0 + (t+1) * 64;
            const float* kp = kT + (h*LDIM + kt + cS) * DDIM + dq*8;
            k0n = *(const float4*)kp; k1n = *(const float4*)(kp + 4);
            const float* vp = vT + (h*LDIM + kt + cS) * DDIM + dq*8;
            v0n = *(const float4*)vp; v1n = *(const float4*)(vp + 4);
            if (tid < 64) pkn = pos[kt + tid];
        }
        __syncthreads();   // (B) staging visible

        f32x4 Sf[4];
        #pragma unroll
        for (int t4 = 0; t4 < 4; ++t4) {
            short8 bhi = *((const short8*)&khi[(t4*64 + lane)*8]);
            short8 blo = *((const short8*)&klo[(t4*64 + lane)*8]);
            f32x4 acc = {0.f, 0.f, 0.f, 0.f};
            acc = __builtin_amdgcn_mfma_f32_16x16x32_bf16(qlo, bhi, acc, 0, 0, 0);
            acc = __builtin_amdgcn_mfma_f32_16x16x32_bf16(qhi, blo, acc, 0, 0, 0);
            acc = __builtin_amdgcn_mfma_f32_16x16x32_bf16(qhi, bhi, acc, 0, 0, 0);
            Sf[t4] = acc;
        }

        float ev[4][4];
        float rmax[4] = {-INFINITY, -INFINITY, -INFINITY, -INFINITY};
        #pragma unroll
        for (int t4 = 0; t4 < 4; ++t4) {
            const float pkt = pk[16*t4 + n];
            #pragma unroll
            for (int i = 0; i < 4; ++i) {
                float s = fmaf(Sf[t4][i], 0.0625f, cq[i] * __logf(fabsf(pq[i] - pkt) + 1.f));
                ev[t4][i] = s;
                rmax[i] = fmaxf(rmax[i], s);
            }
        }
        #pragma unroll
        for (int off = 1; off < 16; off <<= 1)
            #pragma unroll
            for (int i = 0; i < 4; ++i)
                rmax[i] = fmaxf(rmax[i], __shfl_xor(rmax[i], off, 64));

        float al[4], rsum[4];
        #pragma unroll
        for (int i = 0; i < 4; ++i) {
            const float mn = fmaxf(m[i], rmax[i]);
            al[i] = __expf(m[i] - mn);
            m[i] = mn;
            rsum[i] = 0.f;
        }
        #pragma unroll
        for (int t4 = 0; t4 < 4; ++t4)
            #pragma unroll
            for (int i = 0; i < 4; ++i) {
                float e = __expf(ev[t4][i] - m[i]);
                ev[t4][i] = e;
                rsum[i] += e;
            }
        #pragma unroll
        for (int off = 1; off < 16; off <<= 1)
            #pragma unroll
            for (int i = 0; i < 4; ++i)
                rsum[i] += __shfl_xor(rsum[i], off, 64);
        #pragma unroll
        for (int i = 0; i < 4; ++i) l[i] = l[i]*al[i] + rsum[i];

        if (n == 0) {
            #pragma unroll
            for (int i = 0; i < 4; ++i) alph[qs0 + 4*quad + i] = al[i];
        }
        #pragma unroll
        for (int t4 = 0; t4 < 4; ++t4) {
            float4 w; w.x = ev[t4][0]; w.y = ev[t4][1]; w.z = ev[t4][2]; w.w = ev[t4][3];
            *(float4*)&ps_t[16*t4 + n][qs0 + 4*quad] = w;
        }
        __syncthreads();   // (C) ps_t/alph visible

        {
            float4 a4 = *(const float4*)&alph[pr0];
            o[0][0]*=a4.x; o[0][1]*=a4.x; o[1][0]*=a4.y; o[1][1]*=a4.y;
            o[2][0]*=a4.z; o[2][1]*=a4.z; o[3][0]*=a4.w; o[3][1]*=a4.w;
        }
        #pragma unroll 4
        for (int c = 0; c < 64; ++c) {
            float4 p4 = *(const float4*)&ps_t[c][pr0];
            float2 v2 = *(const float2*)&vs[c][dg2];
            o[0][0] += p4.x*v2.x; o[0][1] += p4.x*v2.y;
            o[1][0] += p4.y*v2.x; o[1][1] += p4.y*v2.y;
            o[2][0] += p4.z*v2.x; o[2][1] += p4.z*v2.y;
            o[3][0] += p4.w*v2.x; o[3][1] += p4.w*v2.y;
        }

        k0c = k0n; k1c = k1n; v0c = v0n; v1c = v1n; pkc = pkn;
    }

    const int ph = p * HDIM + h;
    #pragma unroll
    for (int i = 0; i < 4; ++i) {
        float2 w; w.x = o[i][0]; w.y = o[i][1];
        *(float2*)(Op + ((size_t)ph*LDIM + q0 + pr0 + i)*DDIM + dg2) = w;
    }
    if (n == 0) {
        #pragma unroll
        for (int i = 0; i < 4; ++i) {
            const int r = q0 + qs0 + 4*quad + i;
            Mp[ph*LDIM + r] = m[i];
            Lp[ph*LDIM + r] = l[i];
        }
    }
}

// ---------------------------------------------------------------------------
// combine_kernel: A(L,E) = normalized combine of P attention partials, output
// directly as split-bf16 (hi, lo) for the MFMA output projection.
// 65536 threads (256 blocks), one float4 of A per thread.
// ---------------------------------------------------------------------------
__global__ __launch_bounds__(256) void combine_kernel(
    const float* __restrict__ Op, const float* __restrict__ Mp, const float* __restrict__ Lp,
    int P, short* __restrict__ Ah, short* __restrict__ Al)
{
    const int idx = blockIdx.x * 256 + threadIdx.x;   // 0..65535
    const int n  = idx >> 6;
    const int e4 = (idx & 63) * 4;
    const int h  = e4 >> 5;
    const int d  = e4 & 31;

    float mv[8], lv[8];
    float mx = -INFINITY;
    #pragma unroll
    for (int p = 0; p < 8; ++p) if (p < P) {
        mv[p] = Mp[(p*HDIM + h)*LDIM + n];
        lv[p] = Lp[(p*HDIM + h)*LDIM + n];
        mx = fmaxf(mx, mv[p]);
    }
    float s = 0.f;
    #pragma unroll
    for (int p = 0; p < 8; ++p) if (p < P) {
        float a = __expf(mv[p] - mx);
        mv[p] = a;
        s += a * lv[p];
    }
    const float inv = 1.f / s;

    float x[4] = {0.f, 0.f, 0.f, 0.f};
    #pragma unroll
    for (int p = 0; p < 8; ++p) if (p < P) {
        const float sp = mv[p] * inv;
        float4 xp = *(const float4*)(Op + ((size_t)(p*HDIM + h)*LDIM + n)*DDIM + d);
        x[0] += sp*xp.x; x[1] += sp*xp.y; x[2] += sp*xp.z; x[3] += sp*xp.w;
    }
    short4v hi, lo;
    #pragma unroll
    for (int j = 0; j < 4; ++j) {
        unsigned short hh = bf16h(x[j]);
        hi[j] = (short)hh;
        lo[j] = (short)bf16h(x[j] - bf16tof(hh));
    }
    *(short4v*)&Ah[n*EDIM + e4] = hi;
    *(short4v*)&Al[n*EDIM + e4] = lo;
}

// ---------------------------------------------------------------------------
// outproj_kernel (MFMA): out(L,E) = A(L,E) @ Wo(E,E)^T + bo, split-bf16
// 3-term MFMA, direct global fragment loads. 32x32 tile, 128 thr (2 waves x
// 2 col-tiles), grid (32,8) = 256 blocks.
// ---------------------------------------------------------------------------
__global__ __launch_bounds__(128) void outproj_kernel(
    const short* __restrict__ Ah, const short* __restrict__ Al,
    const short* __restrict__ Woh, const short* __restrict__ Wol,
    const float* __restrict__ bo, float* __restrict__ out)
{
    const int n0 = blockIdx.x * 32;
    const int o0 = blockIdx.y * 32;
    const int wave = threadIdx.x >> 6;
    const int lane = threadIdx.x & 63;
    const int n16  = lane & 15;
    const int quad = lane >> 4;

    const int mrow = n0 + wave*16 + n16;

    f32x4 acc[2];
    acc[0] = (f32x4){0.f,0.f,0.f,0.f};
    acc[1] = (f32x4){0.f,0.f,0.f,0.f};

    #pragma unroll 2
    for (int kb = 0; kb < EDIM; kb += 32) {
        short8 ah = *(const short8*)&Ah[mrow*EDIM + kb + quad*8];
        short8 al = *(const short8*)&Al[mrow*EDIM + kb + quad*8];
        #pragma unroll
        for (int t2 = 0; t2 < 2; ++t2) {
            const int orow = o0 + 16*t2 + n16;
            short8 bh = *(const short8*)&Woh[orow*EDIM + kb + quad*8];
            short8 bl = *(const short8*)&Wol[orow*EDIM + kb + quad*8];
            acc[t2] = __builtin_amdgcn_mfma_f32_16x16x32_bf16(al, bh, acc[t2], 0, 0, 0);
            acc[t2] = __builtin_amdgcn_mfma_f32_16x16x32_bf16(ah, bl, acc[t2], 0, 0, 0);
            acc[t2] = __builtin_amdgcn_mfma_f32_16x16x32_bf16(ah, bh, acc[t2], 0, 0, 0);
        }
    }

    #pragma unroll
    for (int t2 = 0; t2 < 2; ++t2) {
        const int o = o0 + 16*t2 + n16;
        const float b = bo[o];
        #pragma unroll
        for (int i = 0; i < 4; ++i) {
            const int r = n0 + wave*16 + quad*4 + i;
            out[r*EDIM + o] = acc[t2][i] + b;
        }
    }
}

// ---------------------------------------------------------------------------
extern "C" void kernel_launch(void* const* d_in, const int* in_sizes, int n_in,
                              void* d_out, int out_size, void* d_ws, size_t ws_size,
                              hipStream_t stream) {
    const float* V   = (const float*)d_in[0];
    const float* K   = (const float*)d_in[1];
    const float* Q   = (const float*)d_in[2];
    const float* pos = (const float*)d_in[3];
    const float* Wq  = (const float*)d_in[4];
    const float* Wk  = (const float*)d_in[5];
    const float* Wv  = (const float*)d_in[6];
    const float* Wr  = (const float*)d_in[7];
    const float* Wo  = (const float*)d_in[8];
    const float* bo  = (const float*)d_in[9];
    float* out = (float*)d_out;
    float* ws  = (float*)d_ws;

    // ---- workspace layout (float units) ----
    short* Wqh = (short*)(ws);          short* Wql = (short*)(ws + 32768);
    short* Wkh = (short*)(ws + 65536);  short* Wkl = (short*)(ws + 98304);
    short* Wvh = (short*)(ws + 131072); short* Wvl = (short*)(ws + 163840);
    short* Woh = (short*)(ws + 196608); short* Wol = (short*)(ws + 229376);
    float* qT    = ws + 262144;
    float* kT    = ws + 524288;
    float* vT    = ws + 786432;
    float* coeff = ws + 1048576;
    short* Ah    = (short*)(ws + 1056768);   // 262144 shorts
    short* Al    = (short*)(ws + 1187840);
    float* Op    = ws + 1319040;

    auto need = [](int P) -> size_t {
        return (size_t)(1319040 + P*278528) * 4;
    };
    int P = 2;
    if (ws_size >= need(8)) P = 8;
    else if (ws_size >= need(4)) P = 4;

    float* Mp = Op + (size_t)P * 262144;
    float* Lp = Mp + (size_t)P * 8192;

    convertw_kernel<<<dim3(32, 4),    256, 0, stream>>>(Wq, Wk, Wv, Wo,
        Wqh, Wql, Wkh, Wkl, Wvh, Wvl, Woh, Wol);
    proj_kernel    <<<dim3(32, 4, 3), 128, 0, stream>>>(Q, K, V,
        Wqh, Wql, Wkh, Wkl, Wvh, Wvl, Wr, qT, kT, vT, coeff);
    attn_kernel    <<<dim3(16, 8, P), 256, 0, stream>>>(qT, kT, vT, coeff, pos,
        Op, Mp, Lp, 16 / P);
    combine_kernel <<<dim3(256),      256, 0, stream>>>(Op, Mp, Lp, P, Ah, Al);
    outproj_kernel <<<dim3(32, 8),    128, 0, stream>>>(Ah, Al, Woh, Wol, bo, out);
}